// Round 20
// baseline (410.994 us; speedup 1.0000x reference)
//
#include <hip/hip_runtime.h>
#include <math.h>

// AttentionBlock: B=8, C=256, HW=4096. Round 20: R18 (best, 394.5us) + VALU diet:
//   - exp2 trick: Q prescaled by 0.0625*log2(e) -> softmax exp = bare v_exp_f32
//     (2^x native), deleting 16 v_mul/lane/tile. RTHR in log2 units (11.5).
//   - balanced-tree max/sum reductions (depth 15 -> 4; max3-fusable).
//   attn is 1 wave/SIMD (VGPR 200) so VALU-path cycles convert ~1:1 to time.
//   K1/K1b/K2/K4 structure unchanged from R18.
// ws: s,t 16KB | Qt 16M | Kt 16M | Vb 16M | nxT 16M | tmpT 16M

#define Bn 8
#define Cn 256
#define HWn 4096
#define Gn 8
#define CPGn 32
#define Mqkv 768
#define EPSf 1e-5f
#define QSCALEf 0.09016844f   // (1/16) * log2(e): S arrives in log2 units
#define RTHR2 11.5f           // 8 * log2(e), defer-rescale threshold in log2 units

typedef short bf16x8 __attribute__((ext_vector_type(8)));
typedef float f32x4 __attribute__((ext_vector_type(4)));
typedef float f32x16 __attribute__((ext_vector_type(16)));

__device__ __forceinline__ unsigned short f2bf(float f) {
  union { float f; unsigned u; } v; v.f = f;
  unsigned r = v.u + 0x7FFFu + ((v.u >> 16) & 1u);  // RNE
  return (unsigned short)(r >> 16);
}

__device__ __forceinline__ int cvt_pk_bf16(float lo, float hi) {
  int d;
  asm("v_cvt_pk_bf16_f32 %0, %1, %2" : "=v"(d) : "v"(lo), "v"(hi));
  return d;
}

__device__ __forceinline__ float exp2_hw(float x) {
  float r;
  asm("v_exp_f32 %0, %1" : "=v"(r) : "v"(x));  // native 2^x
  return r;
}

// ---------------- K1: group-norm stats -> per-channel affine ----------------
__global__ __launch_bounds__(1024)
void gn_stats_kernel(const float* __restrict__ x, const float* __restrict__ gn_w,
                     const float* __restrict__ gn_b, float* __restrict__ s_out,
                     float* __restrict__ t_out) {
  const int b = blockIdx.x / Gn, g = blockIdx.x % Gn;
  const float4* base = (const float4*)(x + ((size_t)(b * Cn + g * CPGn)) * HWn);
  const int n4 = CPGn * HWn / 4;
  float sum = 0.f, sq = 0.f;
  for (int i = threadIdx.x; i < n4; i += 1024) {
    float4 v = base[i];
    sum += (v.x + v.y) + (v.z + v.w);
    sq  += (v.x * v.x + v.y * v.y) + (v.z * v.z + v.w * v.w);
  }
  __shared__ float ss[1024], s2[1024];
  ss[threadIdx.x] = sum; s2[threadIdx.x] = sq;
  __syncthreads();
  for (int off = 512; off > 0; off >>= 1) {
    if ((int)threadIdx.x < off) {
      ss[threadIdx.x] += ss[threadIdx.x + off];
      s2[threadIdx.x] += s2[threadIdx.x + off];
    }
    __syncthreads();
  }
  if (threadIdx.x < CPGn) {
    const float inv_n = 1.f / (float)(CPGn * HWn);
    float mean = ss[0] * inv_n;
    float var  = s2[0] * inv_n - mean * mean;
    float rstd = rsqrtf(var + EPSf);
    int c = g * CPGn + (int)threadIdx.x;
    float sc = gn_w[c] * rstd;
    s_out[b * Cn + c] = sc;
    t_out[b * Cn + c] = gn_b[c] - mean * sc;
  }
}

// ---------------- K1b: affine + transpose -> nxT[b][n][c] bf16 ----------------
__global__ __launch_bounds__(256)
void affine_transpose_kernel(const float* __restrict__ x, const float* __restrict__ s_aff,
                             const float* __restrict__ t_aff, unsigned short* __restrict__ nxT) {
  const int bid = blockIdx.x;
  const int b = bid & 7, r = bid >> 3;
  const int c0 = (r & 3) * 64, n0 = (r >> 2) * 64;
  const int tid = threadIdx.x;
  __shared__ unsigned int ld32[64][33];
  const float* xb = x + ((size_t)(b * Cn + c0)) * HWn + n0;
  const int cl0 = tid >> 4, nn = (tid & 15) * 4;
#pragma unroll
  for (int it = 0; it < 4; ++it) {
    int cl = cl0 + 16 * it;
    int c = c0 + cl;
    float sc = s_aff[b * Cn + c], sh = t_aff[b * Cn + c];
    float4 v = *(const float4*)(xb + (size_t)cl * HWn + nn);
    ld32[cl][(nn >> 1) + 0] = (unsigned)cvt_pk_bf16(v.x * sc + sh, v.y * sc + sh);
    ld32[cl][(nn >> 1) + 1] = (unsigned)cvt_pk_bf16(v.z * sc + sh, v.w * sc + sh);
  }
  __syncthreads();
#pragma unroll
  for (int it = 0; it < 2; ++it) {
    int chunk = tid + 256 * it;
    int n = chunk >> 3, cg = chunk & 7;
    union { unsigned short u[8]; bf16x8 v; } o;
#pragma unroll
    for (int k = 0; k < 8; ++k) {
      unsigned w32 = ld32[cg * 8 + k][n >> 1];
      o.u[k] = (unsigned short)((n & 1) ? (w32 >> 16) : (w32 & 0xffffu));
    }
    *(bf16x8*)(nxT + ((size_t)(b * HWn + n0 + n)) * Cn + c0 + cg * 8) = o.v;
  }
}

// ---------------- K2: QKV GEMM, LDS-free bf16 MFMA ----------------
__global__ __launch_bounds__(256, 2)
void qkv_gemm_kernel(const unsigned short* __restrict__ nxT, const float* __restrict__ w,
                     const float* __restrict__ wb, unsigned short* __restrict__ Qt,
                     unsigned short* __restrict__ Kt, unsigned short* __restrict__ Vb) {
  const int bid = blockIdx.x;
  const int b = bid & 7, r = bid >> 3;
  const int n0 = (r & 63) * 64, m0 = (r >> 6) * 128;
  const int tid = threadIdx.x;
  const int wv = tid >> 6, l = tid & 63;
  const int l15 = l & 15, lq = l >> 4;
  const int ob = m0 + wv * 32;

  bf16x8 wf[2][8];
#pragma unroll
  for (int g = 0; g < 2; ++g) {
    const float* wr = w + (size_t)(ob + g * 16 + l15) * Cn + lq * 8;
#pragma unroll
    for (int kc = 0; kc < 8; ++kc) {
      float4 a = *(const float4*)(wr + kc * 32);
      float4 c4 = *(const float4*)(wr + kc * 32 + 4);
      union { int w4[4]; bf16x8 v; } u;
      u.w4[0] = cvt_pk_bf16(a.x, a.y);  u.w4[1] = cvt_pk_bf16(a.z, a.w);
      u.w4[2] = cvt_pk_bf16(c4.x, c4.y); u.w4[3] = cvt_pk_bf16(c4.z, c4.w);
      wf[g][kc] = u.v;
    }
  }

  const unsigned short* nb = nxT + (size_t)b * HWn * Cn + lq * 8;
  f32x4 acc[2][4];
#pragma unroll
  for (int g = 0; g < 2; ++g)
#pragma unroll
    for (int s = 0; s < 4; ++s) acc[g][s] = (f32x4)(0.f);

  const bool isV = (m0 >= 512);
#pragma unroll
  for (int s = 0; s < 4; ++s) {
    const unsigned short* np = nb + (size_t)(n0 + s * 16 + l15) * Cn;
#pragma unroll
    for (int kc = 0; kc < 8; ++kc) {
      bf16x8 xf = *(const bf16x8*)(np + kc * 32);
      if (!isV) {
        acc[0][s] = __builtin_amdgcn_mfma_f32_16x16x32_bf16(wf[0][kc], xf, acc[0][s], 0, 0, 0);
        acc[1][s] = __builtin_amdgcn_mfma_f32_16x16x32_bf16(wf[1][kc], xf, acc[1][s], 0, 0, 0);
      } else {
        acc[0][s] = __builtin_amdgcn_mfma_f32_16x16x32_bf16(xf, wf[0][kc], acc[0][s], 0, 0, 0);
        acc[1][s] = __builtin_amdgcn_mfma_f32_16x16x32_bf16(xf, wf[1][kc], acc[1][s], 0, 0, 0);
      }
    }
  }

  if (!isV) {
    unsigned short* dst = (m0 < 256) ? Qt : Kt;
    const float scl = (m0 < 256) ? QSCALEf : 1.0f;
#pragma unroll
    for (int g = 0; g < 2; ++g) {
      int cb = ((ob + g * 16) & 255) + lq * 4;
      float b0 = wb[ob + g * 16 + lq * 4 + 0];
      float b1 = wb[ob + g * 16 + lq * 4 + 1];
      float b2 = wb[ob + g * 16 + lq * 4 + 2];
      float b3 = wb[ob + g * 16 + lq * 4 + 3];
#pragma unroll
      for (int s = 0; s < 4; ++s) {
        int n = n0 + s * 16 + l15;
        ushort4 pk;
        pk.x = f2bf((acc[g][s][0] + b0) * scl);
        pk.y = f2bf((acc[g][s][1] + b1) * scl);
        pk.z = f2bf((acc[g][s][2] + b2) * scl);
        pk.w = f2bf((acc[g][s][3] + b3) * scl);
        *(ushort4*)(dst + ((size_t)(b * HWn + n)) * Cn + cb) = pk;
      }
    }
  } else {
#pragma unroll
    for (int g = 0; g < 2; ++g) {
      int o = ob + g * 16 + l15;
      int c = o - 512;
      float bias = wb[o];
#pragma unroll
      for (int s = 0; s < 4; ++s) {
        int n = n0 + s * 16 + lq * 4;
        ushort4 pk;
        pk.x = f2bf(acc[g][s][0] + bias);
        pk.y = f2bf(acc[g][s][1] + bias);
        pk.z = f2bf(acc[g][s][2] + bias);
        pk.w = f2bf(acc[g][s][3] + bias);
        *(ushort4*)(Vb + ((size_t)(b * Cn + c)) * HWn + n) = pk;
      }
    }
  }
}

// ---------------- K3: flash attention, 32 rows/wave, 32x32 MFMA (R18 + exp2) ----------
// grid 256: b=bid&7, i0=(bid>>3)*128. 4 waves x 32 rows x full 256c.
// S in log2 units (Q prescaled by log2e/16); p = 2^(s-m) via native v_exp_f32.
__global__ __launch_bounds__(256, 1)
void attn_kernel(const unsigned short* __restrict__ Qt,
                 const unsigned short* __restrict__ Kt,
                 const unsigned short* __restrict__ Vb,
                 unsigned short* __restrict__ outp) {
  const int bid = blockIdx.x;
  const int b = bid & 7, i0 = (bid >> 3) * 128;
  const int tid = threadIdx.x;
  const int wv = tid >> 6, l = tid & 63;
  const int l31 = l & 31, hi = l >> 5;

  __shared__ unsigned short Ks[8192];  // 16KB: 32j x 256c
  __shared__ unsigned short Vs[8192];  // 16KB: 256c x 32j
  char* KsB = (char*)Ks;
  char* VsB = (char*)Vs;

  const unsigned short* Qb = Qt + ((size_t)b * HWn + i0) * Cn;
  const unsigned short* Kb = Kt + (size_t)b * HWn * Cn;
  const unsigned short* Vg = Vb + (size_t)b * Cn * HWn;

  bf16x8 qf[16];
  {
    const unsigned short* qrow = Qb + (size_t)(wv * 32 + l31) * Cn + hi * 8;
#pragma unroll
    for (int kc = 0; kc < 16; ++kc) qf[kc] = *(const bf16x8*)(qrow + kc * 16);
  }

  const int kco = (((tid >> 6) << 1) | ((tid >> 5) & 1));
  const unsigned short* gK = Kb + (size_t)(tid & 31) * Cn + kco * 8;
  const int vc  = ((tid >> 7) << 5) | (tid & 31);
  const int vjo = ((tid >> 5) & 1) | (((tid >> 6) & 1) << 1);
  const unsigned short* gV = Vg + (size_t)vc * HWn + vjo * 8;

  bf16x8 kst[4], vst[4];
#pragma unroll
  for (int q = 0; q < 4; ++q) kst[q] = *(const bf16x8*)(gK + q * 64);
#pragma unroll
  for (int q = 0; q < 4; ++q) vst[q] = *(const bf16x8*)(gV + (size_t)q * 64 * HWn);
  gK += 32 * Cn; gV += 32;

  f32x16 oa[8];
#pragma unroll
  for (int cb = 0; cb < 8; ++cb) oa[cb] = (f32x16)(0.f);
  float m_i = -INFINITY, l_i = 0.f;  // m in log2 units

#pragma unroll 1
  for (int t = 0; t < 128; ++t) {
#pragma unroll
    for (int q = 0; q < 4; ++q) *(bf16x8*)(KsB + tid * 16 + q * 4096) = kst[q];
#pragma unroll
    for (int q = 0; q < 4; ++q) *(bf16x8*)(VsB + tid * 16 + q * 4096) = vst[q];
    __syncthreads();
    if (t < 127) {
#pragma unroll
      for (int q = 0; q < 4; ++q) kst[q] = *(const bf16x8*)(gK + q * 64);
#pragma unroll
      for (int q = 0; q < 4; ++q) vst[q] = *(const bf16x8*)(gV + (size_t)q * 64 * HWn);
      gK += 32 * Cn; gV += 32;
    }

    // ---- S^T = K Q^T (log2 units) ----
    f32x16 sa = (f32x16)(0.f);
#pragma unroll
    for (int kc = 0; kc < 16; ++kc) {
      bf16x8 kf = *(const bf16x8*)(KsB + l * 16 + kc * 1024);
      sa = __builtin_amdgcn_mfma_f32_32x32x16_bf16(kf, qf[kc], sa, 0, 0, 0);
    }

    // ---- lane-local online softmax, exp2 path, tree reductions ----
    float p[16];
#pragma unroll
    for (int r = 0; r < 16; ++r) p[r] = sa[r];
    float t0 = fmaxf(fmaxf(p[0], p[1]),   fmaxf(p[2], p[3]));
    float t1 = fmaxf(fmaxf(p[4], p[5]),   fmaxf(p[6], p[7]));
    float t2 = fmaxf(fmaxf(p[8], p[9]),   fmaxf(p[10], p[11]));
    float t3 = fmaxf(fmaxf(p[12], p[13]), fmaxf(p[14], p[15]));
    float rm = fmaxf(fmaxf(t0, t1), fmaxf(t2, t3));
    rm = fmaxf(rm, __shfl_xor(rm, 32));
    if (!__all(rm - m_i <= RTHR2)) {
      float mn = fmaxf(m_i, rm);
      float alpha = exp2_hw(m_i - mn);
      m_i = mn;
      l_i *= alpha;
#pragma unroll
      for (int cb = 0; cb < 8; ++cb)
#pragma unroll
        for (int r = 0; r < 16; ++r) oa[cb][r] *= alpha;
    }
#pragma unroll
    for (int r = 0; r < 16; ++r) p[r] = exp2_hw(p[r] - m_i);
    float s0 = ((p[0] + p[1]) + (p[2] + p[3])) + ((p[4] + p[5]) + (p[6] + p[7]));
    float s1 = ((p[8] + p[9]) + (p[10] + p[11])) + ((p[12] + p[13]) + (p[14] + p[15]));
    float rs = s0 + s1;
    rs += __shfl_xor(rs, 32);
    l_i += rs;

    // ---- pack P + exchange across hi halves -> PV B-frags (R18-verified) ----
    int d0 = cvt_pk_bf16(p[0],  p[1]),  d1 = cvt_pk_bf16(p[2],  p[3]);
    int d2 = cvt_pk_bf16(p[4],  p[5]),  d3 = cvt_pk_bf16(p[6],  p[7]);
    int d4 = cvt_pk_bf16(p[8],  p[9]),  d5 = cvt_pk_bf16(p[10], p[11]);
    int d6 = cvt_pk_bf16(p[12], p[13]), d7 = cvt_pk_bf16(p[14], p[15]);
    int x0 = __shfl_xor(d0, 32), x1 = __shfl_xor(d1, 32);
    int x2 = __shfl_xor(d2, 32), x3 = __shfl_xor(d3, 32);
    int x4 = __shfl_xor(d4, 32), x5 = __shfl_xor(d5, 32);
    int x6 = __shfl_xor(d6, 32), x7 = __shfl_xor(d7, 32);
    union { int w[4]; bf16x8 v; } pf0, pf1;
    pf0.w[0] = hi ? x2 : d0; pf0.w[1] = hi ? x3 : d1;
    pf0.w[2] = hi ? d2 : x0; pf0.w[3] = hi ? d3 : x1;
    pf1.w[0] = hi ? x6 : d4; pf1.w[1] = hi ? x7 : d5;
    pf1.w[2] = hi ? d6 : x4; pf1.w[3] = hi ? d7 : x5;

    // ---- O^T += V P^T over full 256 c ----
#pragma unroll
    for (int cb = 0; cb < 8; ++cb) {
      bf16x8 vf0 = *(const bf16x8*)(VsB + l * 16 + (2 * cb + 0) * 1024);
      bf16x8 vf1 = *(const bf16x8*)(VsB + l * 16 + (2 * cb + 1) * 1024);
      oa[cb] = __builtin_amdgcn_mfma_f32_32x32x16_bf16(vf0, pf0.v, oa[cb], 0, 0, 0);
      oa[cb] = __builtin_amdgcn_mfma_f32_32x32x16_bf16(vf1, pf1.v, oa[cb], 0, 0, 0);
    }
    __syncthreads();
  }

  // ---- epilogue: O /= l (lane-local), write tmpT bf16 [n][c] ----
  float il = 1.f / l_i;
  unsigned short* ob = outp + ((size_t)b * HWn + (size_t)(i0 + wv * 32 + l31)) * Cn;
#pragma unroll
  for (int cb = 0; cb < 8; ++cb) {
#pragma unroll
    for (int g = 0; g < 4; ++g) {
      ushort4 s4;
      s4.x = f2bf(oa[cb][g * 4 + 0] * il);
      s4.y = f2bf(oa[cb][g * 4 + 1] * il);
      s4.z = f2bf(oa[cb][g * 4 + 2] * il);
      s4.w = f2bf(oa[cb][g * 4 + 3] * il);
      *(ushort4*)(ob + cb * 32 + 4 * hi + 8 * g) = s4;
    }
  }
}

// ---------------- K4: out projection, LDS-free bf16 MFMA + residual ----------------
__global__ __launch_bounds__(256, 2)
void out_gemm_kernel(const unsigned short* __restrict__ tmpT, const float* __restrict__ w,
                     const float* __restrict__ wb, const float* __restrict__ xres,
                     float* __restrict__ y) {
  const int bid = blockIdx.x;
  const int b = bid & 7, r = bid >> 3;
  const int n0 = (r & 63) * 64, m0 = (r >> 6) * 128;
  const int tid = threadIdx.x;
  const int wv = tid >> 6, l = tid & 63;
  const int l15 = l & 15, lq = l >> 4;
  const int ob = m0 + wv * 32;

  bf16x8 wf[2][8];
#pragma unroll
  for (int g = 0; g < 2; ++g) {
    const float* wr = w + (size_t)(ob + g * 16 + l15) * Cn + lq * 8;
#pragma unroll
    for (int kc = 0; kc < 8; ++kc) {
      float4 a = *(const float4*)(wr + kc * 32);
      float4 c4 = *(const float4*)(wr + kc * 32 + 4);
      union { int w4[4]; bf16x8 v; } u;
      u.w4[0] = cvt_pk_bf16(a.x, a.y);  u.w4[1] = cvt_pk_bf16(a.z, a.w);
      u.w4[2] = cvt_pk_bf16(c4.x, c4.y); u.w4[3] = cvt_pk_bf16(c4.z, c4.w);
      wf[g][kc] = u.v;
    }
  }

  const unsigned short* tb = tmpT + (size_t)b * HWn * Cn + lq * 8;
  f32x4 acc[2][4];
#pragma unroll
  for (int g = 0; g < 2; ++g)
#pragma unroll
    for (int s = 0; s < 4; ++s) acc[g][s] = (f32x4)(0.f);

#pragma unroll
  for (int s = 0; s < 4; ++s) {
    const unsigned short* tp = tb + (size_t)(n0 + s * 16 + l15) * Cn;
#pragma unroll
    for (int kc = 0; kc < 8; ++kc) {
      bf16x8 tf = *(const bf16x8*)(tp + kc * 32);
      acc[0][s] = __builtin_amdgcn_mfma_f32_16x16x32_bf16(tf, wf[0][kc], acc[0][s], 0, 0, 0);
      acc[1][s] = __builtin_amdgcn_mfma_f32_16x16x32_bf16(tf, wf[1][kc], acc[1][s], 0, 0, 0);
    }
  }

#pragma unroll
  for (int g = 0; g < 2; ++g) {
    int o = ob + g * 16 + l15;
    float bias = wb[o];
#pragma unroll
    for (int s = 0; s < 4; ++s) {
      int n = n0 + s * 16 + lq * 4;
      size_t idx = ((size_t)(b * Cn + o)) * HWn + n;
      float4 xr = *(const float4*)(xres + idx);
      float4 out;
      out.x = acc[g][s][0] + bias + xr.x;
      out.y = acc[g][s][1] + bias + xr.y;
      out.z = acc[g][s][2] + bias + xr.z;
      out.w = acc[g][s][3] + bias + xr.w;
      *(float4*)(y + idx) = out;
    }
  }
}

extern "C" void kernel_launch(void* const* d_in, const int* in_sizes, int n_in,
                              void* d_out, int out_size, void* d_ws, size_t ws_size,
                              hipStream_t stream) {
  (void)in_sizes; (void)n_in; (void)out_size; (void)ws_size;
  const float* x     = (const float*)d_in[0];
  const float* gn_w  = (const float*)d_in[1];
  const float* gn_b  = (const float*)d_in[2];
  const float* qkv_w = (const float*)d_in[3];
  const float* qkv_b = (const float*)d_in[4];
  const float* out_w = (const float*)d_in[5];
  const float* out_b = (const float*)d_in[6];
  float* out = (float*)d_out;

  char* ws = (char*)d_ws;
  float* s_aff = (float*)ws;                                   // B*C
  float* t_aff = s_aff + Bn * Cn;                              // B*C
  unsigned short* Qt  = (unsigned short*)(ws + 16384);         // 16MB
  unsigned short* Kt  = Qt  + (size_t)Bn * HWn * Cn;           // 16MB
  unsigned short* Vb  = Kt  + (size_t)Bn * HWn * Cn;           // 16MB
  unsigned short* nxT = Vb  + (size_t)Bn * HWn * Cn;           // 16MB
  unsigned short* tmpT = nxT + (size_t)Bn * HWn * Cn;          // 16MB

  gn_stats_kernel<<<dim3(Bn * Gn), 1024, 0, stream>>>(x, gn_w, gn_b, s_aff, t_aff);
  affine_transpose_kernel<<<dim3(2048), 256, 0, stream>>>(x, s_aff, t_aff, nxT);
  qkv_gemm_kernel<<<dim3(3072), 256, 0, stream>>>(nxT, qkv_w, qkv_b, Qt, Kt, Vb);
  attn_kernel<<<dim3(256), 256, 0, stream>>>(Qt, Kt, Vb, tmpT);
  out_gemm_kernel<<<dim3(1024), 256, 0, stream>>>(tmpT, out_w, out_b, x, out);
}

// Round 21
// 393.824 us; speedup vs baseline: 1.0436x; 1.0436x over previous
//
#include <hip/hip_runtime.h>
#include <math.h>

// AttentionBlock: B=8, C=256, HW=4096. FINAL (= Round 18, best verified: 394.5us,
//   9.6x over fp32 baseline). R19 (split-j) and R20 (exp2 VALU-diet) both regressed;
//   reverting to the verified optimum.
//   K1  gn_stats: per-(b,group) stats -> per-(b,c) affine s,t
//   K1b affine_transpose: nxT[b][n][c] bf16 (GN applied)
//   K2  qkv_gemm: LDS-free bf16 MFMA -> Qt/Kt [n][c] (Q prescaled 1/16), Vb [c][n]
//   K3  attn: flash attention, 32x32x16 MFMA, 32 rows/wave (no QK duplication),
//       chunk-linear LDS (0 bank conflicts), lane-local softmax, defer-rescale,
//       XCD grid (b=bid&7); epilogue writes tmpT[n][c] bf16
//   K4  out_gemm: LDS-free bf16 MFMA (swapped) + bias + residual
// ws: s,t 16KB | Qt 16M | Kt 16M | Vb 16M | nxT 16M | tmpT 16M

#define Bn 8
#define Cn 256
#define HWn 4096
#define Gn 8
#define CPGn 32
#define Mqkv 768
#define EPSf 1e-5f
#define QSCALEf 0.0625f   // 1/sqrt(256), exact in bf16
#define RTHR 8.0f

typedef short bf16x8 __attribute__((ext_vector_type(8)));
typedef float f32x4 __attribute__((ext_vector_type(4)));
typedef float f32x16 __attribute__((ext_vector_type(16)));

__device__ __forceinline__ unsigned short f2bf(float f) {
  union { float f; unsigned u; } v; v.f = f;
  unsigned r = v.u + 0x7FFFu + ((v.u >> 16) & 1u);  // RNE
  return (unsigned short)(r >> 16);
}

__device__ __forceinline__ int cvt_pk_bf16(float lo, float hi) {
  int d;
  asm("v_cvt_pk_bf16_f32 %0, %1, %2" : "=v"(d) : "v"(lo), "v"(hi));
  return d;
}

// ---------------- K1: group-norm stats -> per-channel affine ----------------
__global__ __launch_bounds__(1024)
void gn_stats_kernel(const float* __restrict__ x, const float* __restrict__ gn_w,
                     const float* __restrict__ gn_b, float* __restrict__ s_out,
                     float* __restrict__ t_out) {
  const int b = blockIdx.x / Gn, g = blockIdx.x % Gn;
  const float4* base = (const float4*)(x + ((size_t)(b * Cn + g * CPGn)) * HWn);
  const int n4 = CPGn * HWn / 4;
  float sum = 0.f, sq = 0.f;
  for (int i = threadIdx.x; i < n4; i += 1024) {
    float4 v = base[i];
    sum += (v.x + v.y) + (v.z + v.w);
    sq  += (v.x * v.x + v.y * v.y) + (v.z * v.z + v.w * v.w);
  }
  __shared__ float ss[1024], s2[1024];
  ss[threadIdx.x] = sum; s2[threadIdx.x] = sq;
  __syncthreads();
  for (int off = 512; off > 0; off >>= 1) {
    if ((int)threadIdx.x < off) {
      ss[threadIdx.x] += ss[threadIdx.x + off];
      s2[threadIdx.x] += s2[threadIdx.x + off];
    }
    __syncthreads();
  }
  if (threadIdx.x < CPGn) {
    const float inv_n = 1.f / (float)(CPGn * HWn);
    float mean = ss[0] * inv_n;
    float var  = s2[0] * inv_n - mean * mean;
    float rstd = rsqrtf(var + EPSf);
    int c = g * CPGn + (int)threadIdx.x;
    float sc = gn_w[c] * rstd;
    s_out[b * Cn + c] = sc;
    t_out[b * Cn + c] = gn_b[c] - mean * sc;
  }
}

// ---------------- K1b: affine + transpose -> nxT[b][n][c] bf16 ----------------
__global__ __launch_bounds__(256)
void affine_transpose_kernel(const float* __restrict__ x, const float* __restrict__ s_aff,
                             const float* __restrict__ t_aff, unsigned short* __restrict__ nxT) {
  const int bid = blockIdx.x;
  const int b = bid & 7, r = bid >> 3;
  const int c0 = (r & 3) * 64, n0 = (r >> 2) * 64;
  const int tid = threadIdx.x;
  __shared__ unsigned int ld32[64][33];
  const float* xb = x + ((size_t)(b * Cn + c0)) * HWn + n0;
  const int cl0 = tid >> 4, nn = (tid & 15) * 4;
#pragma unroll
  for (int it = 0; it < 4; ++it) {
    int cl = cl0 + 16 * it;
    int c = c0 + cl;
    float sc = s_aff[b * Cn + c], sh = t_aff[b * Cn + c];
    float4 v = *(const float4*)(xb + (size_t)cl * HWn + nn);
    ld32[cl][(nn >> 1) + 0] = (unsigned)cvt_pk_bf16(v.x * sc + sh, v.y * sc + sh);
    ld32[cl][(nn >> 1) + 1] = (unsigned)cvt_pk_bf16(v.z * sc + sh, v.w * sc + sh);
  }
  __syncthreads();
#pragma unroll
  for (int it = 0; it < 2; ++it) {
    int chunk = tid + 256 * it;
    int n = chunk >> 3, cg = chunk & 7;
    union { unsigned short u[8]; bf16x8 v; } o;
#pragma unroll
    for (int k = 0; k < 8; ++k) {
      unsigned w32 = ld32[cg * 8 + k][n >> 1];
      o.u[k] = (unsigned short)((n & 1) ? (w32 >> 16) : (w32 & 0xffffu));
    }
    *(bf16x8*)(nxT + ((size_t)(b * HWn + n0 + n)) * Cn + c0 + cg * 8) = o.v;
  }
}

// ---------------- K2: QKV GEMM, LDS-free bf16 MFMA ----------------
__global__ __launch_bounds__(256, 2)
void qkv_gemm_kernel(const unsigned short* __restrict__ nxT, const float* __restrict__ w,
                     const float* __restrict__ wb, unsigned short* __restrict__ Qt,
                     unsigned short* __restrict__ Kt, unsigned short* __restrict__ Vb) {
  const int bid = blockIdx.x;
  const int b = bid & 7, r = bid >> 3;
  const int n0 = (r & 63) * 64, m0 = (r >> 6) * 128;
  const int tid = threadIdx.x;
  const int wv = tid >> 6, l = tid & 63;
  const int l15 = l & 15, lq = l >> 4;
  const int ob = m0 + wv * 32;

  bf16x8 wf[2][8];
#pragma unroll
  for (int g = 0; g < 2; ++g) {
    const float* wr = w + (size_t)(ob + g * 16 + l15) * Cn + lq * 8;
#pragma unroll
    for (int kc = 0; kc < 8; ++kc) {
      float4 a = *(const float4*)(wr + kc * 32);
      float4 c4 = *(const float4*)(wr + kc * 32 + 4);
      union { int w4[4]; bf16x8 v; } u;
      u.w4[0] = cvt_pk_bf16(a.x, a.y);  u.w4[1] = cvt_pk_bf16(a.z, a.w);
      u.w4[2] = cvt_pk_bf16(c4.x, c4.y); u.w4[3] = cvt_pk_bf16(c4.z, c4.w);
      wf[g][kc] = u.v;
    }
  }

  const unsigned short* nb = nxT + (size_t)b * HWn * Cn + lq * 8;
  f32x4 acc[2][4];
#pragma unroll
  for (int g = 0; g < 2; ++g)
#pragma unroll
    for (int s = 0; s < 4; ++s) acc[g][s] = (f32x4)(0.f);

  const bool isV = (m0 >= 512);
#pragma unroll
  for (int s = 0; s < 4; ++s) {
    const unsigned short* np = nb + (size_t)(n0 + s * 16 + l15) * Cn;
#pragma unroll
    for (int kc = 0; kc < 8; ++kc) {
      bf16x8 xf = *(const bf16x8*)(np + kc * 32);
      if (!isV) {
        acc[0][s] = __builtin_amdgcn_mfma_f32_16x16x32_bf16(wf[0][kc], xf, acc[0][s], 0, 0, 0);
        acc[1][s] = __builtin_amdgcn_mfma_f32_16x16x32_bf16(wf[1][kc], xf, acc[1][s], 0, 0, 0);
      } else {
        acc[0][s] = __builtin_amdgcn_mfma_f32_16x16x32_bf16(xf, wf[0][kc], acc[0][s], 0, 0, 0);
        acc[1][s] = __builtin_amdgcn_mfma_f32_16x16x32_bf16(xf, wf[1][kc], acc[1][s], 0, 0, 0);
      }
    }
  }

  if (!isV) {
    unsigned short* dst = (m0 < 256) ? Qt : Kt;
    const float scl = (m0 < 256) ? QSCALEf : 1.0f;
#pragma unroll
    for (int g = 0; g < 2; ++g) {
      int cb = ((ob + g * 16) & 255) + lq * 4;
      float b0 = wb[ob + g * 16 + lq * 4 + 0];
      float b1 = wb[ob + g * 16 + lq * 4 + 1];
      float b2 = wb[ob + g * 16 + lq * 4 + 2];
      float b3 = wb[ob + g * 16 + lq * 4 + 3];
#pragma unroll
      for (int s = 0; s < 4; ++s) {
        int n = n0 + s * 16 + l15;
        ushort4 pk;
        pk.x = f2bf((acc[g][s][0] + b0) * scl);
        pk.y = f2bf((acc[g][s][1] + b1) * scl);
        pk.z = f2bf((acc[g][s][2] + b2) * scl);
        pk.w = f2bf((acc[g][s][3] + b3) * scl);
        *(ushort4*)(dst + ((size_t)(b * HWn + n)) * Cn + cb) = pk;
      }
    }
  } else {
#pragma unroll
    for (int g = 0; g < 2; ++g) {
      int o = ob + g * 16 + l15;
      int c = o - 512;
      float bias = wb[o];
#pragma unroll
      for (int s = 0; s < 4; ++s) {
        int n = n0 + s * 16 + lq * 4;
        ushort4 pk;
        pk.x = f2bf(acc[g][s][0] + bias);
        pk.y = f2bf(acc[g][s][1] + bias);
        pk.z = f2bf(acc[g][s][2] + bias);
        pk.w = f2bf(acc[g][s][3] + bias);
        *(ushort4*)(Vb + ((size_t)(b * Cn + c)) * HWn + n) = pk;
      }
    }
  }
}

// ---------------- K3: flash attention, 32x32 MFMA, 32 rows/wave, no duplication --------
// grid 256: b=bid&7, i0=(bid>>3)*128. 4 waves, wave wv owns rows i0+wv*32+l31, full 256c.
// LDS chunk-linear (16B chunks): reads = l*16 + imm; staging writes = tid*16 + q*4096.
// Softmax lane-local (C/D col = i = l&31): 1 shfl_xor(32) per reduce, 0 bank conflicts.
__global__ __launch_bounds__(256, 1)
void attn_kernel(const unsigned short* __restrict__ Qt,
                 const unsigned short* __restrict__ Kt,
                 const unsigned short* __restrict__ Vb,
                 unsigned short* __restrict__ outp) {
  const int bid = blockIdx.x;
  const int b = bid & 7, i0 = (bid >> 3) * 128;
  const int tid = threadIdx.x;
  const int wv = tid >> 6, l = tid & 63;
  const int l31 = l & 31, hi = l >> 5;

  __shared__ unsigned short Ks[8192];  // 16KB: 32j x 256c
  __shared__ unsigned short Vs[8192];  // 16KB: 256c x 32j
  char* KsB = (char*)Ks;
  char* VsB = (char*)Vs;

  const unsigned short* Qb = Qt + ((size_t)b * HWn + i0) * Cn;
  const unsigned short* Kb = Kt + (size_t)b * HWn * Cn;
  const unsigned short* Vg = Vb + (size_t)b * Cn * HWn;

  // hoisted Q (prescaled): B-frag Q[i = i0+wv*32+l31][c = kc*16 + hi*8 + t]
  bf16x8 qf[16];
  {
    const unsigned short* qrow = Qb + (size_t)(wv * 32 + l31) * Cn + hi * 8;
#pragma unroll
    for (int kc = 0; kc < 16; ++kc) qf[kc] = *(const bf16x8*)(qrow + kc * 16);
  }

  // staging maps (thread tid owns slots q*256+tid)
  const int kco = (((tid >> 6) << 1) | ((tid >> 5) & 1));
  const unsigned short* gK = Kb + (size_t)(tid & 31) * Cn + kco * 8;
  const int vc  = ((tid >> 7) << 5) | (tid & 31);
  const int vjo = ((tid >> 5) & 1) | (((tid >> 6) & 1) << 1);
  const unsigned short* gV = Vg + (size_t)vc * HWn + vjo * 8;

  bf16x8 kst[4], vst[4];
#pragma unroll
  for (int q = 0; q < 4; ++q) kst[q] = *(const bf16x8*)(gK + q * 64);
#pragma unroll
  for (int q = 0; q < 4; ++q) vst[q] = *(const bf16x8*)(gV + (size_t)q * 64 * HWn);
  gK += 32 * Cn; gV += 32;

  f32x16 oa[8];
#pragma unroll
  for (int cb = 0; cb < 8; ++cb) oa[cb] = (f32x16)(0.f);
  float m_i = -INFINITY, l_i = 0.f;

#pragma unroll 1
  for (int t = 0; t < 128; ++t) {
#pragma unroll
    for (int q = 0; q < 4; ++q) *(bf16x8*)(KsB + tid * 16 + q * 4096) = kst[q];
#pragma unroll
    for (int q = 0; q < 4; ++q) *(bf16x8*)(VsB + tid * 16 + q * 4096) = vst[q];
    __syncthreads();
    if (t < 127) {
#pragma unroll
      for (int q = 0; q < 4; ++q) kst[q] = *(const bf16x8*)(gK + q * 64);
#pragma unroll
      for (int q = 0; q < 4; ++q) vst[q] = *(const bf16x8*)(gV + (size_t)q * 64 * HWn);
      gK += 32 * Cn; gV += 32;
    }

    // ---- S^T = K Q^T: one 32x32 tile, lane holds S[j 16 vals][i=l31] ----
    f32x16 sa = (f32x16)(0.f);
#pragma unroll
    for (int kc = 0; kc < 16; ++kc) {
      bf16x8 kf = *(const bf16x8*)(KsB + l * 16 + kc * 1024);
      sa = __builtin_amdgcn_mfma_f32_32x32x16_bf16(kf, qf[kc], sa, 0, 0, 0);
    }

    // ---- lane-local online softmax (row i=l31; j split across hi pair) ----
    float p[16];
#pragma unroll
    for (int r = 0; r < 16; ++r) p[r] = sa[r];
    float rm = p[0];
#pragma unroll
    for (int r = 1; r < 16; ++r) rm = fmaxf(rm, p[r]);
    rm = fmaxf(rm, __shfl_xor(rm, 32));
    if (!__all(rm - m_i <= RTHR)) {
      float mn = fmaxf(m_i, rm);
      float alpha = __expf(m_i - mn);
      m_i = mn;
      l_i *= alpha;
#pragma unroll
      for (int cb = 0; cb < 8; ++cb)
#pragma unroll
        for (int r = 0; r < 16; ++r) oa[cb][r] *= alpha;
    }
    float rs = 0.f;
#pragma unroll
    for (int r = 0; r < 16; ++r) { p[r] = __expf(p[r] - m_i); rs += p[r]; }
    rs += __shfl_xor(rs, 32);
    l_i += rs;

    // ---- pack P + exchange across hi halves -> PV B-frags ----
    int d0 = cvt_pk_bf16(p[0],  p[1]),  d1 = cvt_pk_bf16(p[2],  p[3]);
    int d2 = cvt_pk_bf16(p[4],  p[5]),  d3 = cvt_pk_bf16(p[6],  p[7]);
    int d4 = cvt_pk_bf16(p[8],  p[9]),  d5 = cvt_pk_bf16(p[10], p[11]);
    int d6 = cvt_pk_bf16(p[12], p[13]), d7 = cvt_pk_bf16(p[14], p[15]);
    int x0 = __shfl_xor(d0, 32), x1 = __shfl_xor(d1, 32);
    int x2 = __shfl_xor(d2, 32), x3 = __shfl_xor(d3, 32);
    int x4 = __shfl_xor(d4, 32), x5 = __shfl_xor(d5, 32);
    int x6 = __shfl_xor(d6, 32), x7 = __shfl_xor(d7, 32);
    union { int w[4]; bf16x8 v; } pf0, pf1;
    pf0.w[0] = hi ? x2 : d0; pf0.w[1] = hi ? x3 : d1;
    pf0.w[2] = hi ? d2 : x0; pf0.w[3] = hi ? d3 : x1;
    pf1.w[0] = hi ? x6 : d4; pf1.w[1] = hi ? x7 : d5;
    pf1.w[2] = hi ? d6 : x4; pf1.w[3] = hi ? d7 : x5;

    // ---- O^T += V P^T over full 256 c (8 c-blocks x 2 j-chunks) ----
#pragma unroll
    for (int cb = 0; cb < 8; ++cb) {
      bf16x8 vf0 = *(const bf16x8*)(VsB + l * 16 + (2 * cb + 0) * 1024);
      bf16x8 vf1 = *(const bf16x8*)(VsB + l * 16 + (2 * cb + 1) * 1024);
      oa[cb] = __builtin_amdgcn_mfma_f32_32x32x16_bf16(vf0, pf0.v, oa[cb], 0, 0, 0);
      oa[cb] = __builtin_amdgcn_mfma_f32_32x32x16_bf16(vf1, pf1.v, oa[cb], 0, 0, 0);
    }
    __syncthreads();
  }

  // ---- epilogue: O /= l (lane-local), write tmpT bf16 [n][c] ----
  float il = 1.f / l_i;
  unsigned short* ob = outp + ((size_t)b * HWn + (size_t)(i0 + wv * 32 + l31)) * Cn;
#pragma unroll
  for (int cb = 0; cb < 8; ++cb) {
#pragma unroll
    for (int g = 0; g < 4; ++g) {
      ushort4 s4;
      s4.x = f2bf(oa[cb][g * 4 + 0] * il);
      s4.y = f2bf(oa[cb][g * 4 + 1] * il);
      s4.z = f2bf(oa[cb][g * 4 + 2] * il);
      s4.w = f2bf(oa[cb][g * 4 + 3] * il);
      *(ushort4*)(ob + cb * 32 + 4 * hi + 8 * g) = s4;
    }
  }
}

// ---------------- K4: out projection, LDS-free bf16 MFMA + residual ----------------
__global__ __launch_bounds__(256, 2)
void out_gemm_kernel(const unsigned short* __restrict__ tmpT, const float* __restrict__ w,
                     const float* __restrict__ wb, const float* __restrict__ xres,
                     float* __restrict__ y) {
  const int bid = blockIdx.x;
  const int b = bid & 7, r = bid >> 3;
  const int n0 = (r & 63) * 64, m0 = (r >> 6) * 128;
  const int tid = threadIdx.x;
  const int wv = tid >> 6, l = tid & 63;
  const int l15 = l & 15, lq = l >> 4;
  const int ob = m0 + wv * 32;

  bf16x8 wf[2][8];
#pragma unroll
  for (int g = 0; g < 2; ++g) {
    const float* wr = w + (size_t)(ob + g * 16 + l15) * Cn + lq * 8;
#pragma unroll
    for (int kc = 0; kc < 8; ++kc) {
      float4 a = *(const float4*)(wr + kc * 32);
      float4 c4 = *(const float4*)(wr + kc * 32 + 4);
      union { int w4[4]; bf16x8 v; } u;
      u.w4[0] = cvt_pk_bf16(a.x, a.y);  u.w4[1] = cvt_pk_bf16(a.z, a.w);
      u.w4[2] = cvt_pk_bf16(c4.x, c4.y); u.w4[3] = cvt_pk_bf16(c4.z, c4.w);
      wf[g][kc] = u.v;
    }
  }

  const unsigned short* tb = tmpT + (size_t)b * HWn * Cn + lq * 8;
  f32x4 acc[2][4];
#pragma unroll
  for (int g = 0; g < 2; ++g)
#pragma unroll
    for (int s = 0; s < 4; ++s) acc[g][s] = (f32x4)(0.f);

#pragma unroll
  for (int s = 0; s < 4; ++s) {
    const unsigned short* tp = tb + (size_t)(n0 + s * 16 + l15) * Cn;
#pragma unroll
    for (int kc = 0; kc < 8; ++kc) {
      bf16x8 tf = *(const bf16x8*)(tp + kc * 32);
      acc[0][s] = __builtin_amdgcn_mfma_f32_16x16x32_bf16(tf, wf[0][kc], acc[0][s], 0, 0, 0);
      acc[1][s] = __builtin_amdgcn_mfma_f32_16x16x32_bf16(tf, wf[1][kc], acc[1][s], 0, 0, 0);
    }
  }

#pragma unroll
  for (int g = 0; g < 2; ++g) {
    int o = ob + g * 16 + l15;
    float bias = wb[o];
#pragma unroll
    for (int s = 0; s < 4; ++s) {
      int n = n0 + s * 16 + lq * 4;
      size_t idx = ((size_t)(b * Cn + o)) * HWn + n;
      float4 xr = *(const float4*)(xres + idx);
      float4 out;
      out.x = acc[g][s][0] + bias + xr.x;
      out.y = acc[g][s][1] + bias + xr.y;
      out.z = acc[g][s][2] + bias + xr.z;
      out.w = acc[g][s][3] + bias + xr.w;
      *(float4*)(y + idx) = out;
    }
  }
}

extern "C" void kernel_launch(void* const* d_in, const int* in_sizes, int n_in,
                              void* d_out, int out_size, void* d_ws, size_t ws_size,
                              hipStream_t stream) {
  (void)in_sizes; (void)n_in; (void)out_size; (void)ws_size;
  const float* x     = (const float*)d_in[0];
  const float* gn_w  = (const float*)d_in[1];
  const float* gn_b  = (const float*)d_in[2];
  const float* qkv_w = (const float*)d_in[3];
  const float* qkv_b = (const float*)d_in[4];
  const float* out_w = (const float*)d_in[5];
  const float* out_b = (const float*)d_in[6];
  float* out = (float*)d_out;

  char* ws = (char*)d_ws;
  float* s_aff = (float*)ws;                                   // B*C
  float* t_aff = s_aff + Bn * Cn;                              // B*C
  unsigned short* Qt  = (unsigned short*)(ws + 16384);         // 16MB
  unsigned short* Kt  = Qt  + (size_t)Bn * HWn * Cn;           // 16MB
  unsigned short* Vb  = Kt  + (size_t)Bn * HWn * Cn;           // 16MB
  unsigned short* nxT = Vb  + (size_t)Bn * HWn * Cn;           // 16MB
  unsigned short* tmpT = nxT + (size_t)Bn * HWn * Cn;          // 16MB

  gn_stats_kernel<<<dim3(Bn * Gn), 1024, 0, stream>>>(x, gn_w, gn_b, s_aff, t_aff);
  affine_transpose_kernel<<<dim3(2048), 256, 0, stream>>>(x, s_aff, t_aff, nxT);
  qkv_gemm_kernel<<<dim3(3072), 256, 0, stream>>>(nxT, qkv_w, qkv_b, Qt, Kt, Vb);
  attn_kernel<<<dim3(256), 256, 0, stream>>>(Qt, Kt, Vb, tmpT);
  out_gemm_kernel<<<dim3(1024), 256, 0, stream>>>(tmpT, out_w, out_b, x, out);
}